// Round 5
// baseline (441.663 us; speedup 1.0000x reference)
//
#include <hip/hip_runtime.h>
#include <hip/hip_bf16.h>

// Problem constants
#define Bb 2
#define Ss 2048
#define Ee 2048
#define Hh 16
#define Dd 128
#define Mrows (Bb*Ss)   // 4096

typedef short short8 __attribute__((ext_vector_type(8)));
typedef float f32x4 __attribute__((ext_vector_type(4)));

__device__ __forceinline__ unsigned short bf_rne(float f) {
    unsigned u = __builtin_bit_cast(unsigned, f);
    u += 0x7fffu + ((u >> 16) & 1u);
    return (unsigned short)(u >> 16);
}
__device__ __forceinline__ float bf2f(unsigned short x) {
    unsigned u = ((unsigned)x) << 16;
    return __builtin_bit_cast(float, u);
}
__device__ __forceinline__ void load_lds16(const void* g, void* l) {
    __builtin_amdgcn_global_load_lds(
        (const __attribute__((address_space(1))) unsigned int*)g,
        (__attribute__((address_space(3))) unsigned int*)l, 16, 0, 0);
}

// ---------------- fused fp32 -> bf16 cast of all 6 tensors (unchanged) ----------------
__global__ void cast_all_kernel(const float4* __restrict__ xq, const float4* __restrict__ xkv,
                                const float4* __restrict__ wq, const float4* __restrict__ wk,
                                const float4* __restrict__ wv, const float4* __restrict__ wo,
                                ushort4* __restrict__ out) {
    int i = blockIdx.x * 256 + threadIdx.x;
    const float4* src;
    int rel;
    if (i < 2097152)       { src = xq;  rel = i; }
    else if (i < 4194304)  { src = xkv; rel = i - 2097152; }
    else if (i < 5242880)  { src = wq;  rel = i - 4194304; }
    else if (i < 6291456)  { src = wk;  rel = i - 5242880; }
    else if (i < 7340032)  { src = wv;  rel = i - 6291456; }
    else                   { src = wo;  rel = i - 7340032; }
    float4 v = src[rel];
    ushort4 o;
    o.x = bf_rne(v.x); o.y = bf_rne(v.y); o.z = bf_rne(v.z); o.w = bf_rne(v.w);
    out[i] = o;
}

// ---------------- GEMM core v4.1: phase-interleaved, 256x128 tile, BK=64 --------------
// 512 threads = 8 waves (4M x 2N), per-wave 64x64 output (acc[4][4]).
// LDS: 3 buffers x 48KB (A 256x64 = 32KB, B 128x64 = 16KB) = 144KB -> 1 block/CU.
// LDS row r (128B) holds global row r of the tile, chunk c (16B) at slot c^(r&7).
// Per K-tile two PHASES (k-slice 0/1), m201-template sync per phase:
//   {8 ds_read_b128 frags + 3 global_load_lds staging issues}
//   __builtin_amdgcn_s_barrier();
//   asm("s_waitcnt lgkmcnt(0)"); sched_barrier(0);      <- rule 18 fence
//   setprio(1); 16 MFMA; setprio(0); sched_barrier(0);
//   __builtin_amdgcn_s_barrier();
// Tile boundary (end of phase B) is the counted "s_waitcnt vmcnt(6); s_barrier"
// (single asm, memory clobber). Stage 2 tiles ahead.
// Ledger: stage at iter t writes buf (t+2)%3 whose last readers finished before the
// iter-(t-1) boundary barrier (WAR safe); vmcnt(6) at iter-t boundary retires exactly
// tile t+1's 6 issues (6 youngest are t+2's), barrier publishes (RAW safe).
// Tail: vmcnt(0) at t==NT8-2.
#define NT8 32          // K tiles = 2048/64
#define BUF8 49152      // bytes per LDS buffer (A 32768 + B 16384)

__device__ __forceinline__ void gemm_core8(
    const short* __restrict__ A, const short* __restrict__ W,
    int m0, int n0, char* lds, f32x4 (&acc)[4][4], int tid)
{
    const int wid  = tid >> 6, lane = tid & 63;
    const int wr   = wid >> 1, wc   = wid & 1;
    const int quad = lane >> 4, l16 = lane & 15;
    const int lr   = lane >> 3, sl  = lane & 7;
    const int g    = sl ^ lr;                       // swizzled global chunk

    // staging source: issue `is` covers tile rows is*64 + wid*8 + lr
    const short* Ap = A + (size_t)(m0 + wid*8 + lr) * Ee + g*8;
    const short* Wp = W + (size_t)(n0 + wid*8 + lr) * Ee + g*8;

    auto stageHalf = [&](int kt, int so, int ih) {   // 2 A issues + 1 B issue
        #pragma unroll
        for (int i = 0; i < 2; ++i) {
            int is = ih*2 + i;
            load_lds16(Ap + (size_t)is*64*Ee + kt*64, lds + so + is*8192 + wid*1024);
        }
        load_lds16(Wp + (size_t)ih*64*Ee + kt*64, lds + so + 32768 + ih*8192 + wid*1024);
    };

    const int arow = (wr*64 + l16) * 128;   // byte offset of A frag row
    const int brow = (wc*64 + l16) * 128;   // byte offset of B frag row

    #define LDSFRAGS(bo, ks)                                                          \
        {                                                                             \
            const int cofs = (((ks)*4 + quad) ^ (l16 & 7)) << 4;                      \
            _Pragma("unroll")                                                         \
            for (int i2 = 0; i2 < 4; ++i2)                                            \
                af[i2] = *(const short8*)(lds + (bo) + arow + i2*2048 + cofs);        \
            _Pragma("unroll")                                                         \
            for (int j = 0; j < 4; ++j)                                               \
                bfr[j] = *(const short8*)(lds + (bo) + 32768 + brow + j*2048 + cofs); \
        }

    #define MFMA16()                                                                  \
        {                                                                             \
            __builtin_amdgcn_s_setprio(1);                                            \
            _Pragma("unroll")                                                         \
            for (int i2 = 0; i2 < 4; ++i2)                                            \
                _Pragma("unroll")                                                     \
                for (int j = 0; j < 4; ++j)                                           \
                    acc[i2][j] = __builtin_amdgcn_mfma_f32_16x16x32_bf16(             \
                        af[i2], bfr[j], acc[i2][j], 0, 0, 0);                         \
            __builtin_amdgcn_s_setprio(0);                                            \
        }

    // m201-template phase sync: barrier, explicit lgkm drain, hoist fence (rule 18)
    #define PHASE_ENTER()                                                             \
        __builtin_amdgcn_s_barrier();                                                 \
        asm volatile("s_waitcnt lgkmcnt(0)" ::: "memory");                            \
        __builtin_amdgcn_sched_barrier(0);

    #define PHASE_EXIT()                                                              \
        __builtin_amdgcn_sched_barrier(0);                                            \
        __builtin_amdgcn_s_barrier();

    // prologue: tiles 0 and 1
    stageHalf(0, 0, 0);    stageHalf(0, 0, 1);
    stageHalf(1, BUF8, 0); stageHalf(1, BUF8, 1);
    asm volatile("s_waitcnt vmcnt(6)\n\ts_barrier" ::: "memory");

    int bo = 0, so = 2*BUF8;
    for (int t = 0; t < NT8; ++t) {
        short8 af[4], bfr[4];
        // ---- phase A (k-slice 0)
        LDSFRAGS(bo, 0)
        if (t + 2 < NT8) stageHalf(t+2, so, 0);
        PHASE_ENTER()
        MFMA16()
        PHASE_EXIT()
        // ---- phase B (k-slice 1)
        LDSFRAGS(bo, 1)
        if (t + 2 < NT8) stageHalf(t+2, so, 1);
        PHASE_ENTER()
        MFMA16()
        __builtin_amdgcn_sched_barrier(0);
        if (t == NT8 - 1) break;
        if (t < NT8 - 2) asm volatile("s_waitcnt vmcnt(6)\n\ts_barrier" ::: "memory");
        else             asm volatile("s_waitcnt vmcnt(0)\n\ts_barrier" ::: "memory");
        bo = (bo == 2*BUF8) ? 0 : bo + BUF8;
        so = (so == 2*BUF8) ? 0 : so + BUF8;
    }
    #undef LDSFRAGS
    #undef MFMA16
    #undef PHASE_ENTER
    #undef PHASE_EXIT
}

// ---------------- fused QKV projection ----------------
// grid (16, 48), 512 threads: by>>4 = sub (0=Q,1=K,2=V), by&15 = head (n-block of 128).
// Q,K -> [B,H,S,D] bf16. V -> [B,H,D,S] bf16 via per-wave 64x64 LDS transpose.
__global__ __launch_bounds__(512, 2) void qkv_gemm(
    const short* __restrict__ xq, const short* __restrict__ xkv,
    const short* __restrict__ wq, const short* __restrict__ wk, const short* __restrict__ wv,
    const float* __restrict__ bq, const float* __restrict__ bk, const float* __restrict__ bv,
    short* __restrict__ Qr, short* __restrict__ Kr, short* __restrict__ VT)
{
    __shared__ __align__(16) char lds[147456];   // 3 x 48KB
    const int tid  = threadIdx.x;
    const int wid  = tid >> 6, lane = tid & 63;
    const int quad = lane >> 4, l16 = lane & 15;
    const int wr   = wid >> 1, wc   = wid & 1;
    const int m0   = blockIdx.x * 256;
    const int sub  = blockIdx.y >> 4;
    const int nb   = blockIdx.y & 15;
    const int n0   = nb * 128;

    const short* A = (sub == 0) ? xq : xkv;
    const short* W = (sub == 0) ? wq : (sub == 1) ? wk : wv;
    const float* bias = (sub == 0) ? bq : (sub == 1) ? bk : bv;

    f32x4 acc[4][4] = {};
    gemm_core8(A, W, m0, n0, lds, acc, tid);

    const int b0 = m0 >> 11;
    const int s0 = m0 & (Ss - 1);

    if (sub < 2) {
        short* out = sub ? Kr : Qr;
        #pragma unroll
        for (int i2 = 0; i2 < 4; ++i2)
            #pragma unroll
            for (int j = 0; j < 4; ++j)
                #pragma unroll
                for (int r = 0; r < 4; ++r) {
                    int gm = m0 + wr*64 + i2*16 + quad*4 + r;
                    int d  = wc*64 + j*16 + l16;
                    float v = acc[i2][j][r] + bias[n0 + d];
                    int b = gm >> 11, s = gm & (Ss - 1);
                    out[(((size_t)(b*Hh + nb)) * Ss + s) * Dd + d] = (short)bf_rne(v);
                }
    } else {
        // V: per-wave 64x64 transpose. Wave owns s in [wr*64,+64), d in [wc*64,+64).
        __syncthreads();   // all waves done with staging LDS before reuse
        short* T = (short*)lds + wid * 4608;   // 64 d-rows x stride 72 shorts (9216 B/wave)
        #pragma unroll
        for (int i2 = 0; i2 < 4; ++i2)
            #pragma unroll
            for (int j = 0; j < 4; ++j)
                #pragma unroll
                for (int r = 0; r < 4; ++r) {
                    int dl  = j*16 + l16;
                    int slc = i2*16 + quad*4 + r;
                    T[dl*72 + slc] = (short)bf_rne(acc[i2][j][r] + bias[n0 + wc*64 + dl]);
                }
        __syncthreads();
        #pragma unroll
        for (int ss = 0; ss < 8; ++ss) {
            short8 v = *(const short8*)&T[lane*72 + ss*8];
            int dg = wc*64 + lane;
            int sg = s0 + wr*64 + ss*8;
            *(short8*)&VT[(((size_t)(b0*Hh + nb)) * Dd + dg) * Ss + sg] = v;
        }
    }
}

// ---------------- O-projection: fp32 out = Ob @ wo^T + bo ----------------
__global__ __launch_bounds__(512, 2) void oproj_gemm(
    const short* __restrict__ A, const short* __restrict__ W,
    const float* __restrict__ bias, float* __restrict__ Cf)
{
    __shared__ __align__(16) char lds[147456];
    const int tid  = threadIdx.x;
    const int wid  = tid >> 6, lane = tid & 63;
    const int quad = lane >> 4, l16 = lane & 15;
    const int wr   = wid >> 1, wc   = wid & 1;
    const int m0   = blockIdx.x * 256;
    const int n0   = blockIdx.y * 128;

    f32x4 acc[4][4] = {};
    gemm_core8(A, W, m0, n0, lds, acc, tid);

    #pragma unroll
    for (int i2 = 0; i2 < 4; ++i2)
        #pragma unroll
        for (int j = 0; j < 4; ++j)
            #pragma unroll
            for (int r = 0; r < 4; ++r) {
                int gm = m0 + wr*64 + i2*16 + quad*4 + r;
                int gn = n0 + wc*64 + j*16 + l16;
                Cf[(size_t)gm * Ee + gn] = acc[i2][j][r] + bias[gn];
            }
}

// ---------------- RoPE in place on [B,H,S,D] bf16 (unchanged) ----------------
__global__ void rope_kernel(short* __restrict__ Qr, short* __restrict__ Kr,
                            const float* __restrict__ cosT, const float* __restrict__ sinT) {
    short* X    = blockIdx.y ? Kr : Qr;
    float scale = blockIdx.y ? 1.0f : 0.08838834764831845f;
    int idx = blockIdx.x * 256 + threadIdx.x;
    int d  = idx & 63;
    int s  = (idx >> 6) & (Ss - 1);
    int bh = idx >> 17;
    size_t base = ((size_t)bh * Ss + s) * Dd;
    float x1 = bf2f((unsigned short)X[base + d]);
    float x2 = bf2f((unsigned short)X[base + d + 64]);
    float c  = cosT[s*Dd + d];
    float sn = sinT[s*Dd + d];
    X[base + d]      = (short)bf_rne((x1 * c - x2 * sn) * scale);
    X[base + d + 64] = (short)bf_rne((x2 * c + x1 * sn) * scale);
}

// ---------------- Flash attention (causal), bf16 MFMA (unchanged) ----------------
__global__ __launch_bounds__(256, 2) void attn_kernel(
    const short* __restrict__ Q, const short* __restrict__ Kk,
    const short* __restrict__ VT, short* __restrict__ O)
{
    __shared__ short Ks[64*128];
    __shared__ short Vt[2][128*64];
    __shared__ short Pw[4][32*72];

    const int tid  = threadIdx.x;
    const int wave = tid >> 6;
    const int lane = tid & 63;
    const int quad = lane >> 4;
    const int l16  = lane & 15;
    const int mmap = (blockIdx.x + blockIdx.y) & 15;
    const int qt   = (blockIdx.y & 16) ? (15 - mmap) : mmap;
    const int bh = blockIdx.y;
    const int b  = bh >> 4, h = bh & 15;
    const size_t head_off = (size_t)bh * Ss * Dd;
    const short* Kg  = Kk + head_off;
    const short* VTg = VT + head_off;

    auto stageK = [&](int kt) {
        #pragma unroll
        for (int j = 0; j < 4; ++j) {
            int r = wave*16 + j*4 + (lane >> 4);
            int c = (lane & 15) ^ (r & 15);
            load_lds16(Kg + (size_t)(kt*64 + r)*Dd + c*8, &Ks[(wave*16 + j*4)*128]);
        }
    };
    auto stageV = [&](int kt, int buf) {
        #pragma unroll
        for (int j = 0; j < 4; ++j) {
            int r = wave*32 + j*8 + (lane >> 3);
            int c = (lane & 7) ^ (r & 7);
            load_lds16(VTg + (size_t)r*Ss + kt*64 + c*8, &Vt[buf][(wave*32 + j*8)*64]);
        }
    };

    const int qbase = qt*128 + wave*32;
    short8 qf[2][4];
    #pragma unroll
    for (int mi = 0; mi < 2; ++mi)
        #pragma unroll
        for (int ds = 0; ds < 4; ++ds)
            qf[mi][ds] = *(const short8*)&Q[head_off + (size_t)(qbase + mi*16 + l16)*Dd + ds*32 + quad*8];

    f32x4 o[2][8] = {};
    float m_i[2][4], l_i[2][4];
    #pragma unroll
    for (int mi = 0; mi < 2; ++mi)
        #pragma unroll
        for (int r = 0; r < 4; ++r) { m_i[mi][r] = -__builtin_inff(); l_i[mi][r] = 0.f; }

    const int ktiles = 2*qt + 2;
    stageK(0);
    stageV(0, 0);

    for (int kt = 0; kt < ktiles; ++kt) {
        __syncthreads();
        if (kt + 1 < ktiles) stageV(kt+1, (kt+1)&1);

        f32x4 sc[2][4] = {};
        #pragma unroll
        for (int jk = 0; jk < 4; ++jk)
            #pragma unroll
            for (int ds = 0; ds < 4; ++ds) {
                short8 kf = *(const short8*)&Ks[(jk*16 + l16)*128 + (((ds*4 + quad) ^ l16) * 8)];
                #pragma unroll
                for (int mi = 0; mi < 2; ++mi)
                    sc[mi][jk] = __builtin_amdgcn_mfma_f32_16x16x32_bf16(qf[mi][ds], kf, sc[mi][jk], 0, 0, 0);
            }

        __syncthreads();
        if (kt + 1 < ktiles) stageK(kt+1);

        const int k0 = kt*64;
        #pragma unroll
        for (int mi = 0; mi < 2; ++mi) {
            if (k0 + 63 > qbase + mi*16) {
                #pragma unroll
                for (int jk = 0; jk < 4; ++jk) {
                    int kg = k0 + jk*16 + l16;
                    #pragma unroll
                    for (int r = 0; r < 4; ++r)
                        if (kg > qbase + mi*16 + quad*4 + r) sc[mi][jk][r] = -__builtin_inff();
                }
            }
        }

        float alpha[2][4];
        #pragma unroll
        for (int mi = 0; mi < 2; ++mi)
            #pragma unroll
            for (int r = 0; r < 4; ++r) {
                float mx = fmaxf(fmaxf(sc[mi][0][r], sc[mi][1][r]), fmaxf(sc[mi][2][r], sc[mi][3][r]));
                #pragma unroll
                for (int off = 1; off < 16; off <<= 1)
                    mx = fmaxf(mx, __shfl_xor(mx, off));
                float mn = fmaxf(m_i[mi][r], mx);
                alpha[mi][r] = __expf(m_i[mi][r] - mn);
                m_i[mi][r] = mn;
                float s = 0.f;
                #pragma unroll
                for (int jk = 0; jk < 4; ++jk) {
                    float p = __expf(sc[mi][jk][r] - mn);
                    sc[mi][jk][r] = p;
                    s += p;
                }
                l_i[mi][r] = l_i[mi][r] * alpha[mi][r] + s;
            }

        #pragma unroll
        for (int mi = 0; mi < 2; ++mi)
            #pragma unroll
            for (int jk = 0; jk < 4; ++jk)
                #pragma unroll
                for (int r = 0; r < 4; ++r)
                    Pw[wave][(mi*16 + quad*4 + r)*72 + jk*16 + l16] = (short)bf_rne(sc[mi][jk][r]);

        #pragma unroll
        for (int mi = 0; mi < 2; ++mi)
            #pragma unroll
            for (int dt = 0; dt < 8; ++dt)
                #pragma unroll
                for (int r = 0; r < 4; ++r)
                    o[mi][dt][r] *= alpha[mi][r];

        short8 pa[2][2];
        #pragma unroll
        for (int mi = 0; mi < 2; ++mi)
            #pragma unroll
            for (int kk = 0; kk < 2; ++kk)
                pa[mi][kk] = *(const short8*)&Pw[wave][(mi*16 + l16)*72 + kk*32 + quad*8];

        const short* vb = Vt[kt & 1];
        #pragma unroll
        for (int dt = 0; dt < 8; ++dt)
            #pragma unroll
            for (int kk = 0; kk < 2; ++kk) {
                short8 vf = *(const short8*)&vb[(dt*16 + l16)*64 + (((kk*4 + quad) ^ (l16 & 7)) * 8)];
                #pragma unroll
                for (int mi = 0; mi < 2; ++mi)
                    o[mi][dt] = __builtin_amdgcn_mfma_f32_16x16x32_bf16(pa[mi][kk], vf, o[mi][dt], 0, 0, 0);
            }
    }

    #pragma unroll
    for (int mi = 0; mi < 2; ++mi)
        #pragma unroll
        for (int r = 0; r < 4; ++r) {
            float l = l_i[mi][r];
            #pragma unroll
            for (int off = 1; off < 16; off <<= 1)
                l += __shfl_xor(l, off);
            float inv = 1.0f / l;
            int srow = qbase + mi*16 + quad*4 + r;
            size_t obase = ((size_t)b * Ss + srow) * Ee + h * Dd;
            #pragma unroll
            for (int dt = 0; dt < 8; ++dt)
                O[obase + dt*16 + l16] = (short)bf_rne(o[mi][dt][r] * inv);
        }
}

extern "C" void kernel_launch(void* const* d_in, const int* in_sizes, int n_in,
                              void* d_out, int out_size, void* d_ws, size_t ws_size,
                              hipStream_t stream) {
    const float* x_q  = (const float*)d_in[0];
    const float* x_kv = (const float*)d_in[1];
    const float* cosT = (const float*)d_in[2];
    const float* sinT = (const float*)d_in[3];
    const float* wq = (const float*)d_in[4];
    const float* bq = (const float*)d_in[5];
    const float* wk = (const float*)d_in[6];
    const float* bk = (const float*)d_in[7];
    const float* wv = (const float*)d_in[8];
    const float* bv = (const float*)d_in[9];
    const float* wo = (const float*)d_in[10];
    const float* bo = (const float*)d_in[11];

    size_t off = 0;
    auto alloc = [&](size_t bytes) {
        void* p = (char*)d_ws + off;
        off += (bytes + 255) & ~(size_t)255;
        return p;
    };
    const size_t nX = (size_t)Mrows * Ee;
    const size_t nW = (size_t)Ee * Ee;
    // NOTE: the 6 cast outputs must stay contiguous (cast_all writes them as one run)
    short* xq16  = (short*)alloc(nX * 2);
    short* xkv16 = (short*)alloc(nX * 2);
    short* wq16  = (short*)alloc(nW * 2);
    short* wk16  = (short*)alloc(nW * 2);
    short* wv16  = (short*)alloc(nW * 2);
    short* wo16  = (short*)alloc(nW * 2);
    short* Qr    = (short*)alloc(nX * 2);      // [B,H,S,D]
    short* Kr    = (short*)alloc(nX * 2);      // [B,H,S,D]
    short* VTb   = (short*)alloc(nX * 2);      // [B,H,D,S]
    short* Ob    = (short*)alloc(nX * 2);      // [B,S,E]

    // 1) single fused cast
    cast_all_kernel<<<32768, 256, 0, stream>>>(
        (const float4*)x_q, (const float4*)x_kv, (const float4*)wq,
        (const float4*)wk, (const float4*)wv, (const float4*)wo, (ushort4*)xq16);

    // 2) fused QKV projection (Q,K -> [B,H,S,D]; V -> [B,H,D,S])
    qkv_gemm<<<dim3(Mrows/256, 48), 512, 0, stream>>>(
        xq16, xkv16, wq16, wk16, wv16, bq, bk, bv, Qr, Kr, VTb);

    // 3) RoPE on Q (1/sqrt(D) folded) and K, one dispatch
    rope_kernel<<<dim3((Bb*Hh*Ss*64)/256, 2), 256, 0, stream>>>(Qr, Kr, cosT, sinT);

    // 4) causal flash attention -> Ob [B,S,E] bf16
    attn_kernel<<<dim3(16, Bb*Hh), 256, 0, stream>>>(Qr, Kr, VTb, Ob);

    // 5) output projection -> fp32 d_out
    oproj_gemm<<<dim3(Mrows/256, Ee/128), 512, 0, stream>>>(Ob, wo16, bo, (float*)d_out);
}

// Round 6
// 437.272 us; speedup vs baseline: 1.0100x; 1.0100x over previous
//
#include <hip/hip_runtime.h>
#include <hip/hip_bf16.h>

// Problem constants
#define Bb 2
#define Ss 2048
#define Ee 2048
#define Hh 16
#define Dd 128
#define Mrows (Bb*Ss)   // 4096

typedef short short8 __attribute__((ext_vector_type(8)));
typedef float f32x4 __attribute__((ext_vector_type(4)));

__device__ __forceinline__ unsigned short bf_rne(float f) {
    unsigned u = __builtin_bit_cast(unsigned, f);
    u += 0x7fffu + ((u >> 16) & 1u);
    return (unsigned short)(u >> 16);
}
__device__ __forceinline__ float bf2f(unsigned short x) {
    unsigned u = ((unsigned)x) << 16;
    return __builtin_bit_cast(float, u);
}
__device__ __forceinline__ void load_lds16(const void* g, void* l) {
    __builtin_amdgcn_global_load_lds(
        (const __attribute__((address_space(1))) unsigned int*)g,
        (__attribute__((address_space(3))) unsigned int*)l, 16, 0, 0);
}

// ---------------- fused fp32 -> bf16 cast of all 6 tensors (unchanged) ----------------
__global__ void cast_all_kernel(const float4* __restrict__ xq, const float4* __restrict__ xkv,
                                const float4* __restrict__ wq, const float4* __restrict__ wk,
                                const float4* __restrict__ wv, const float4* __restrict__ wo,
                                ushort4* __restrict__ out) {
    int i = blockIdx.x * 256 + threadIdx.x;
    const float4* src;
    int rel;
    if (i < 2097152)       { src = xq;  rel = i; }
    else if (i < 4194304)  { src = xkv; rel = i - 2097152; }
    else if (i < 5242880)  { src = wq;  rel = i - 4194304; }
    else if (i < 6291456)  { src = wk;  rel = i - 5242880; }
    else if (i < 7340032)  { src = wv;  rel = i - 6291456; }
    else                   { src = wo;  rel = i - 7340032; }
    float4 v = src[rel];
    ushort4 o;
    o.x = bf_rne(v.x); o.y = bf_rne(v.y); o.z = bf_rne(v.z); o.w = bf_rne(v.w);
    out[i] = o;
}

#define NTK 64          // K tiles = 2048/32

// ---------------- GEMM core v3 (qkv, round-3 verified): 256x128, BK=32, dbuf 48KB ----
// 48KB LDS -> 3 blocks/CU, grid 768 = exactly 3/CU. Register-lean K-loop (bf[4] held,
// af streamed) for 3 waves/SIMD. Boundary: fused "s_waitcnt vmcnt(0); s_barrier".
// Ledger: stage at iter t writes buf (t+1)&1 last read at iter t-1 (WAR safe, reads
// retired before that iter's fused barrier); compute at t reads buf t&1 staged at t-1
// and drained by the boundary vmcnt(0) (RAW safe).
__device__ __forceinline__ void gemm_core_db(
    const short* __restrict__ A, const short* __restrict__ W,
    int m0, int n0, char* lds, f32x4 (&acc)[8][4], int tid)
{
    const int wid  = tid >> 6, lane = tid & 63;
    const int wr   = wid >> 1, wc   = wid & 1;
    const int quad = lane >> 4, l16 = lane & 15;
    const int lr   = lane >> 3, sl  = lane & 7;
    const int g    = sl ^ lr;                      // swizzled global chunk
    const int grow = 2*(wid*8 + lr) + (g >> 2);    // global row within a 64-row slab
    const int kcol = (g & 3) * 8;                  // k-chunk (shorts) within 32-wide tile
    const int cx16 = ((((l16 & 1) << 2) + quad) ^ ((l16 >> 1) & 7)) << 4;
    const int arow = (l16 >> 1) << 7;              // ds-row byte offset within frag group

    const short* Ap = A + (size_t)(m0 + grow) * Ee + kcol;
    const short* Wp = W + (size_t)(n0 + grow) * Ee + kcol;

    // prologue: stage tile 0 into buf0
    #pragma unroll
    for (int i = 0; i < 4; ++i)
        load_lds16(Ap + (size_t)i*64*Ee, lds + i*4096 + wid*1024);
    #pragma unroll
    for (int i = 0; i < 2; ++i)
        load_lds16(Wp + (size_t)i*64*Ee, lds + 16384 + i*4096 + wid*1024);
    Ap += 32; Wp += 32;
    asm volatile("s_waitcnt vmcnt(0)\n\ts_barrier" ::: "memory");

    for (int t = 0; t < NTK; ++t) {
        const int bo = (t & 1) ? 24576 : 0;
        if (t + 1 < NTK) {
            const int so = bo ^ 24576;
            #pragma unroll
            for (int i = 0; i < 4; ++i)
                load_lds16(Ap + (size_t)i*64*Ee, lds + so + i*4096 + wid*1024);
            #pragma unroll
            for (int i = 0; i < 2; ++i)
                load_lds16(Wp + (size_t)i*64*Ee, lds + so + 16384 + i*4096 + wid*1024);
            Ap += 32; Wp += 32;
        }
        const char* Ab2 = lds + bo + wr*8192 + arow + cx16;
        const char* Bb2 = lds + bo + 16384 + wc*4096 + arow + cx16;
        short8 bfr[4];
        #pragma unroll
        for (int j = 0; j < 4; ++j) bfr[j] = *(const short8*)(Bb2 + j*1024);
        __builtin_amdgcn_s_setprio(1);
        #pragma unroll
        for (int i = 0; i < 8; ++i) {
            short8 af = *(const short8*)(Ab2 + i*1024);   // streamed, not held
            #pragma unroll
            for (int j = 0; j < 4; ++j)
                acc[i][j] = __builtin_amdgcn_mfma_f32_16x16x32_bf16(af, bfr[j], acc[i][j], 0, 0, 0);
        }
        __builtin_amdgcn_s_setprio(0);
        asm volatile("s_waitcnt vmcnt(0)\n\ts_barrier" ::: "memory");
    }
}

// ---------------- GEMM core v2.1 (oproj, rounds-2/3 verified): 3-buf counted vmcnt ----
#define BUFB 24576      // bytes per LDS buffer

__device__ __forceinline__ void gemm_core(
    const short* __restrict__ A, const short* __restrict__ W,
    int m0, int n0, char* lds, f32x4 (&acc)[8][4], int tid)
{
    const int wid  = tid >> 6, lane = tid & 63;
    const int wr   = wid >> 1, wc   = wid & 1;
    const int quad = lane >> 4, l16 = lane & 15;
    const int lr   = lane >> 3, sl  = lane & 7;
    const int g    = sl ^ lr;
    const int grow = 2*(wid*8 + lr) + (g >> 2);
    const int kcol = (g & 3) * 8;
    const int cx16 = ((((l16 & 1) << 2) + quad) ^ ((l16 >> 1) & 7)) << 4;
    const int arow = (l16 >> 1) << 7;

    const short* Ab = A + (size_t)(m0 + grow) * Ee + kcol;
    const short* Wb = W + (size_t)(n0 + grow) * Ee + kcol;

    auto stageTile = [&](int kt, int so) {
        const short* a = Ab + kt * 32;
        const short* w = Wb + kt * 32;
        #pragma unroll
        for (int i = 0; i < 4; ++i)
            load_lds16(a + (size_t)i*64*Ee, lds + so + i*4096 + wid*1024);
        #pragma unroll
        for (int i = 0; i < 2; ++i)
            load_lds16(w + (size_t)i*64*Ee, lds + so + 16384 + i*4096 + wid*1024);
    };

    stageTile(0, 0);
    stageTile(1, BUFB);
    asm volatile("s_waitcnt vmcnt(6)\n\ts_barrier" ::: "memory");

    int bo = 0, so = 2*BUFB;
    for (int t = 0; t < NTK; ++t) {
        if (t + 2 < NTK) stageTile(t + 2, so);

        const char* Abase = lds + bo + wr*8192 + arow + cx16;
        const char* Bbase = lds + bo + 16384 + wc*4096 + arow + cx16;
        short8 af[8], bfr[4];
        #pragma unroll
        for (int i = 0; i < 8; ++i) af[i] = *(const short8*)(Abase + i*1024);
        #pragma unroll
        for (int j = 0; j < 4; ++j) bfr[j] = *(const short8*)(Bbase + j*1024);

        __builtin_amdgcn_s_setprio(1);
        #pragma unroll
        for (int i = 0; i < 8; ++i)
            #pragma unroll
            for (int j = 0; j < 4; ++j)
                acc[i][j] = __builtin_amdgcn_mfma_f32_16x16x32_bf16(af[i], bfr[j], acc[i][j], 0, 0, 0);
        __builtin_amdgcn_s_setprio(0);

        if (t == NTK - 1) break;
        if (t < NTK - 2) asm volatile("s_waitcnt vmcnt(6)\n\ts_barrier" ::: "memory");
        else             asm volatile("s_waitcnt vmcnt(0)\n\ts_barrier" ::: "memory");
        bo = (bo == 2*BUFB) ? 0 : bo + BUFB;
        so = (so == 2*BUFB) ? 0 : so + BUFB;
    }
}

// ---------------- fused QKV projection (round-3 verified) ----------------
__global__ __launch_bounds__(256, 3) void qkv_gemm(
    const short* __restrict__ xq, const short* __restrict__ xkv,
    const short* __restrict__ wq, const short* __restrict__ wk, const short* __restrict__ wv,
    const float* __restrict__ bq, const float* __restrict__ bk, const float* __restrict__ bv,
    short* __restrict__ Qr, short* __restrict__ Kr, short* __restrict__ VT)
{
    __shared__ __align__(16) char lds[49152];   // 2 x 24KB dbuf -> 3 blocks/CU
    const int tid  = threadIdx.x;
    const int wid  = tid >> 6, lane = tid & 63;
    const int quad = lane >> 4, l16 = lane & 15;
    const int wr   = wid >> 1, wc   = wid & 1;
    const int m0   = blockIdx.x * 256;
    const int sub  = blockIdx.y >> 4;
    const int nb   = blockIdx.y & 15;
    const int n0   = nb * 128;

    const short* A = (sub == 0) ? xq : xkv;
    const short* W = (sub == 0) ? wq : (sub == 1) ? wk : wv;
    const float* bias = (sub == 0) ? bq : (sub == 1) ? bk : bv;

    f32x4 acc[8][4] = {};
    gemm_core_db(A, W, m0, n0, lds, acc, tid);

    const int b0 = m0 >> 11;
    const int s0 = m0 & (Ss - 1);

    if (sub < 2) {
        short* out = sub ? Kr : Qr;
        #pragma unroll
        for (int i = 0; i < 8; ++i)
            #pragma unroll
            for (int j = 0; j < 4; ++j)
                #pragma unroll
                for (int r = 0; r < 4; ++r) {
                    int gm = m0 + wr*128 + i*16 + quad*4 + r;
                    int d  = wc*64 + j*16 + l16;
                    float v = acc[i][j][r] + bias[n0 + d];
                    int b = gm >> 11, s = gm & (Ss - 1);
                    out[(((size_t)(b*Hh + nb)) * Ss + s) * Dd + d] = (short)bf_rne(v);
                }
    } else {
        // V: per-wave transpose, two 64-s-row halves to fit 48KB.
        __syncthreads();   // all waves done reading staging LDS before reuse
        short* T = (short*)lds + wid * 4608;   // 9216 B/wave, total 36864 <= 49152
        #pragma unroll
        for (int h = 0; h < 2; ++h) {
            #pragma unroll
            for (int i2 = 0; i2 < 4; ++i2) {
                #pragma unroll
                for (int j = 0; j < 4; ++j)
                    #pragma unroll
                    for (int r = 0; r < 4; ++r) {
                        int dl  = j*16 + l16;
                        int slc = i2*16 + quad*4 + r;
                        T[dl*72 + slc] = (short)bf_rne(acc[h*4 + i2][j][r] + bias[n0 + wc*64 + dl]);
                    }
            }
            #pragma unroll
            for (int ss = 0; ss < 8; ++ss) {
                short8 v = *(const short8*)&T[lane*72 + ss*8];
                int dg = wc*64 + lane;
                int sg = s0 + wr*128 + h*64 + ss*8;
                *(short8*)&VT[(((size_t)(b0*Hh + nb)) * Dd + dg) * Ss + sg] = v;
            }
        }
    }
}

// ---------------- O-projection: fp32 out = Ob @ wo^T + bo (rounds-2/3 verified) -------
__global__ __launch_bounds__(256, 2) void oproj_gemm(
    const short* __restrict__ A, const short* __restrict__ W,
    const float* __restrict__ bias, float* __restrict__ Cf)
{
    __shared__ __align__(16) char lds[73728];
    const int tid  = threadIdx.x;
    const int wid  = tid >> 6, lane = tid & 63;
    const int quad = lane >> 4, l16 = lane & 15;
    const int wr   = wid >> 1, wc   = wid & 1;
    const int m0 = blockIdx.x * 256;
    const int n0 = blockIdx.y * 128;

    f32x4 acc[8][4] = {};
    gemm_core(A, W, m0, n0, lds, acc, tid);

    #pragma unroll
    for (int i = 0; i < 8; ++i)
        #pragma unroll
        for (int j = 0; j < 4; ++j)
            #pragma unroll
            for (int r = 0; r < 4; ++r) {
                int gm = m0 + wr*128 + i*16 + quad*4 + r;
                int gn = n0 + wc*64 + j*16 + l16;
                Cf[(size_t)gm * Ee + gn] = acc[i][j][r] + bias[gn];
            }
}

// ---------------- RoPE in place on [B,H,S,D] bf16 (unchanged) ----------------
__global__ void rope_kernel(short* __restrict__ Qr, short* __restrict__ Kr,
                            const float* __restrict__ cosT, const float* __restrict__ sinT) {
    short* X    = blockIdx.y ? Kr : Qr;
    float scale = blockIdx.y ? 1.0f : 0.08838834764831845f;
    int idx = blockIdx.x * 256 + threadIdx.x;
    int d  = idx & 63;
    int s  = (idx >> 6) & (Ss - 1);
    int bh = idx >> 17;
    size_t base = ((size_t)bh * Ss + s) * Dd;
    float x1 = bf2f((unsigned short)X[base + d]);
    float x2 = bf2f((unsigned short)X[base + d + 64]);
    float c  = cosT[s*Dd + d];
    float sn = sinT[s*Dd + d];
    X[base + d]      = (short)bf_rne((x1 * c - x2 * sn) * scale);
    X[base + d + 64] = (short)bf_rne((x2 * c + x1 * sn) * scale);
}

// ---------------- Flash attention (causal), bf16 MFMA ----------------
// CHANGE vs verified base: the two __syncthreads() per K-tile (each a full
// vmcnt(0)+lgkmcnt(0) drain) are replaced by:
//   top:    "s_waitcnt vmcnt(0); s_barrier"   -- needed: K(t),V(t) staged by all waves
//                                               must be landed+visible before QK^T/PV.
//   middle: "s_waitcnt lgkmcnt(0); s_barrier" -- only guards the Ks WAR hazard (all
//                                               waves' QK^T ds_reads retired before
//                                               stageK(t+1) overwrites Ks). The V(t+1)
//                                               prefetch stays IN FLIGHT across it, so
//                                               PV(t) no longer waits on V(t+1) HBM
//                                               arrival (counted-drain discipline).
// Ledger: stageV(t+1) issued after top barrier of t, drained by top barrier of t+1
// (vmcnt(0)) before PV(t+1) reads it -> RAW safe cross-wave. stageK(t+1) issued after
// middle barrier of t (all QK^T(t) reads done -> WAR safe), drained by top barrier of
// t+1 before QK^T(t+1) -> RAW safe. Pw is per-wave (write->read same wave, compiler
// lgkm waits) -- no barrier needed.
__global__ __launch_bounds__(256, 2) void attn_kernel(
    const short* __restrict__ Q, const short* __restrict__ Kk,
    const short* __restrict__ VT, short* __restrict__ O)
{
    __shared__ short Ks[64*128];
    __shared__ short Vt[2][128*64];
    __shared__ short Pw[4][32*72];

    const int tid  = threadIdx.x;
    const int wave = tid >> 6;
    const int lane = tid & 63;
    const int quad = lane >> 4;
    const int l16  = lane & 15;
    const int mmap = (blockIdx.x + blockIdx.y) & 15;
    const int qt   = (blockIdx.y & 16) ? (15 - mmap) : mmap;
    const int bh = blockIdx.y;
    const int b  = bh >> 4, h = bh & 15;
    const size_t head_off = (size_t)bh * Ss * Dd;
    const short* Kg  = Kk + head_off;
    const short* VTg = VT + head_off;

    auto stageK = [&](int kt) {
        #pragma unroll
        for (int j = 0; j < 4; ++j) {
            int r = wave*16 + j*4 + (lane >> 4);
            int c = (lane & 15) ^ (r & 15);
            load_lds16(Kg + (size_t)(kt*64 + r)*Dd + c*8, &Ks[(wave*16 + j*4)*128]);
        }
    };
    auto stageV = [&](int kt, int buf) {
        #pragma unroll
        for (int j = 0; j < 4; ++j) {
            int r = wave*32 + j*8 + (lane >> 3);
            int c = (lane & 7) ^ (r & 7);
            load_lds16(VTg + (size_t)r*Ss + kt*64 + c*8, &Vt[buf][(wave*32 + j*8)*64]);
        }
    };

    const int qbase = qt*128 + wave*32;
    short8 qf[2][4];
    #pragma unroll
    for (int mi = 0; mi < 2; ++mi)
        #pragma unroll
        for (int ds = 0; ds < 4; ++ds)
            qf[mi][ds] = *(const short8*)&Q[head_off + (size_t)(qbase + mi*16 + l16)*Dd + ds*32 + quad*8];

    f32x4 o[2][8] = {};
    float m_i[2][4], l_i[2][4];
    #pragma unroll
    for (int mi = 0; mi < 2; ++mi)
        #pragma unroll
        for (int r = 0; r < 4; ++r) { m_i[mi][r] = -__builtin_inff(); l_i[mi][r] = 0.f; }

    const int ktiles = 2*qt + 2;
    stageK(0);
    stageV(0, 0);

    for (int kt = 0; kt < ktiles; ++kt) {
        asm volatile("s_waitcnt vmcnt(0)\n\ts_barrier" ::: "memory");
        if (kt + 1 < ktiles) stageV(kt+1, (kt+1)&1);

        f32x4 sc[2][4] = {};
        #pragma unroll
        for (int jk = 0; jk < 4; ++jk)
            #pragma unroll
            for (int ds = 0; ds < 4; ++ds) {
                short8 kf = *(const short8*)&Ks[(jk*16 + l16)*128 + (((ds*4 + quad) ^ l16) * 8)];
                #pragma unroll
                for (int mi = 0; mi < 2; ++mi)
                    sc[mi][jk] = __builtin_amdgcn_mfma_f32_16x16x32_bf16(qf[mi][ds], kf, sc[mi][jk], 0, 0, 0);
            }

        asm volatile("s_waitcnt lgkmcnt(0)\n\ts_barrier" ::: "memory");
        if (kt + 1 < ktiles) stageK(kt+1);

        const int k0 = kt*64;
        #pragma unroll
        for (int mi = 0; mi < 2; ++mi) {
            if (k0 + 63 > qbase + mi*16) {
                #pragma unroll
                for (int jk = 0; jk < 4; ++jk) {
                    int kg = k0 + jk*16 + l16;
                    #pragma unroll
                    for (int r = 0; r < 4; ++r)
                        if (kg > qbase + mi*16 + quad*4 + r) sc[mi][jk][r] = -__builtin_inff();
                }
            }
        }

        float alpha[2][4];
        #pragma unroll
        for (int mi = 0; mi < 2; ++mi)
            #pragma unroll
            for (int r = 0; r < 4; ++r) {
                float mx = fmaxf(fmaxf(sc[mi][0][r], sc[mi][1][r]), fmaxf(sc[mi][2][r], sc[mi][3][r]));
                #pragma unroll
                for (int off = 1; off < 16; off <<= 1)
                    mx = fmaxf(mx, __shfl_xor(mx, off));
                float mn = fmaxf(m_i[mi][r], mx);
                alpha[mi][r] = __expf(m_i[mi][r] - mn);
                m_i[mi][r] = mn;
                float s = 0.f;
                #pragma unroll
                for (int jk = 0; jk < 4; ++jk) {
                    float p = __expf(sc[mi][jk][r] - mn);
                    sc[mi][jk][r] = p;
                    s += p;
                }
                l_i[mi][r] = l_i[mi][r] * alpha[mi][r] + s;
            }

        #pragma unroll
        for (int mi = 0; mi < 2; ++mi)
            #pragma unroll
            for (int jk = 0; jk < 4; ++jk)
                #pragma unroll
                for (int r = 0; r < 4; ++r)
                    Pw[wave][(mi*16 + quad*4 + r)*72 + jk*16 + l16] = (short)bf_rne(sc[mi][jk][r]);

        #pragma unroll
        for (int mi = 0; mi < 2; ++mi)
            #pragma unroll
            for (int dt = 0; dt < 8; ++dt)
                #pragma unroll
                for (int r = 0; r < 4; ++r)
                    o[mi][dt][r] *= alpha[mi][r];

        short8 pa[2][2];
        #pragma unroll
        for (int mi = 0; mi < 2; ++mi)
            #pragma unroll
            for (int kk = 0; kk < 2; ++kk)
                pa[mi][kk] = *(const short8*)&Pw[wave][(mi*16 + l16)*72 + kk*32 + quad*8];

        const short* vb = Vt[kt & 1];
        #pragma unroll
        for (int dt = 0; dt < 8; ++dt)
            #pragma unroll
            for (int kk = 0; kk < 2; ++kk) {
                short8 vf = *(const short8*)&vb[(dt*16 + l16)*64 + (((kk*4 + quad) ^ (l16 & 7)) * 8)];
                #pragma unroll
                for (int mi = 0; mi < 2; ++mi)
                    o[mi][dt] = __builtin_amdgcn_mfma_f32_16x16x32_bf16(pa[mi][kk], vf, o[mi][dt], 0, 0, 0);
            }
    }

    #pragma unroll
    for (int mi = 0; mi < 2; ++mi)
        #pragma unroll
        for (int r = 0; r < 4; ++r) {
            float l = l_i[mi][r];
            #pragma unroll
            for (int off = 1; off < 16; off <<= 1)
                l += __shfl_xor(l, off);
            float inv = 1.0f / l;
            int srow = qbase + mi*16 + quad*4 + r;
            size_t obase = ((size_t)b * Ss + srow) * Ee + h * Dd;
            #pragma unroll
            for (int dt = 0; dt < 8; ++dt)
                O[obase + dt*16 + l16] = (short)bf_rne(o[mi][dt][r] * inv);
        }
}

extern "C" void kernel_launch(void* const* d_in, const int* in_sizes, int n_in,
                              void* d_out, int out_size, void* d_ws, size_t ws_size,
                              hipStream_t stream) {
    const float* x_q  = (const float*)d_in[0];
    const float* x_kv = (const float*)d_in[1];
    const float* cosT = (const float*)d_in[2];
    const float* sinT = (const float*)d_in[3];
    const float* wq = (const float*)d_in[4];
    const float* bq = (const float*)d_in[5];
    const float* wk = (const float*)d_in[6];
    const float* bk = (const float*)d_in[7];
    const float* wv = (const float*)d_in[8];
    const float* bv = (const float*)d_in[9];
    const float* wo = (const float*)d_in[10];
    const float* bo = (const float*)d_in[11];

    size_t off = 0;
    auto alloc = [&](size_t bytes) {
        void* p = (char*)d_ws + off;
        off += (bytes + 255) & ~(size_t)255;
        return p;
    };
    const size_t nX = (size_t)Mrows * Ee;
    const size_t nW = (size_t)Ee * Ee;
    // NOTE: the 6 cast outputs must stay contiguous (cast_all writes them as one run)
    short* xq16  = (short*)alloc(nX * 2);
    short* xkv16 = (short*)alloc(nX * 2);
    short* wq16  = (short*)alloc(nW * 2);
    short* wk16  = (short*)alloc(nW * 2);
    short* wv16  = (short*)alloc(nW * 2);
    short* wo16  = (short*)alloc(nW * 2);
    short* Qr    = (short*)alloc(nX * 2);      // [B,H,S,D]
    short* Kr    = (short*)alloc(nX * 2);      // [B,H,S,D]
    short* VTb   = (short*)alloc(nX * 2);      // [B,H,D,S]
    short* Ob    = (short*)alloc(nX * 2);      // [B,S,E]

    // 1) single fused cast
    cast_all_kernel<<<32768, 256, 0, stream>>>(
        (const float4*)x_q, (const float4*)x_kv, (const float4*)wq,
        (const float4*)wk, (const float4*)wv, (const float4*)wo, (ushort4*)xq16);

    // 2) fused QKV projection (Q,K -> [B,H,S,D]; V -> [B,H,D,S])
    qkv_gemm<<<dim3(Mrows/256, 48), 256, 0, stream>>>(
        xq16, xkv16, wq16, wk16, wv16, bq, bk, bv, Qr, Kr, VTb);

    // 3) RoPE on Q (1/sqrt(D) folded) and K, one dispatch
    rope_kernel<<<dim3((Bb*Hh*Ss*64)/256, 2), 256, 0, stream>>>(Qr, Kr, cosT, sinT);

    // 4) causal flash attention -> Ob [B,S,E] bf16
    attn_kernel<<<dim3(16, Bb*Hh), 256, 0, stream>>>(Qr, Kr, VTb, Ob);

    // 5) output projection -> fp32 d_out
    oproj_gemm<<<dim3(Mrows/256, Ee/128), 256, 0, stream>>>(Ob, wo16, bo, (float*)d_out);
}

// Round 7
// 436.020 us; speedup vs baseline: 1.0129x; 1.0029x over previous
//
#include <hip/hip_runtime.h>
#include <hip/hip_bf16.h>

// Problem constants
#define Bb 2
#define Ss 2048
#define Ee 2048
#define Hh 16
#define Dd 128
#define Mrows (Bb*Ss)   // 4096

typedef short short8 __attribute__((ext_vector_type(8)));
typedef float f32x4 __attribute__((ext_vector_type(4)));

__device__ __forceinline__ unsigned short bf_rne(float f) {
    unsigned u = __builtin_bit_cast(unsigned, f);
    u += 0x7fffu + ((u >> 16) & 1u);
    return (unsigned short)(u >> 16);
}
__device__ __forceinline__ float bf2f(unsigned short x) {
    unsigned u = ((unsigned)x) << 16;
    return __builtin_bit_cast(float, u);
}
__device__ __forceinline__ void load_lds16(const void* g, void* l) {
    __builtin_amdgcn_global_load_lds(
        (const __attribute__((address_space(1))) unsigned int*)g,
        (__attribute__((address_space(3))) unsigned int*)l, 16, 0, 0);
}

// ---------------- fused fp32 -> bf16 cast of all 6 tensors (unchanged) ----------------
__global__ void cast_all_kernel(const float4* __restrict__ xq, const float4* __restrict__ xkv,
                                const float4* __restrict__ wq, const float4* __restrict__ wk,
                                const float4* __restrict__ wv, const float4* __restrict__ wo,
                                ushort4* __restrict__ out) {
    int i = blockIdx.x * 256 + threadIdx.x;
    const float4* src;
    int rel;
    if (i < 2097152)       { src = xq;  rel = i; }
    else if (i < 4194304)  { src = xkv; rel = i - 2097152; }
    else if (i < 5242880)  { src = wq;  rel = i - 4194304; }
    else if (i < 6291456)  { src = wk;  rel = i - 5242880; }
    else if (i < 7340032)  { src = wv;  rel = i - 6291456; }
    else                   { src = wo;  rel = i - 7340032; }
    float4 v = src[rel];
    ushort4 o;
    o.x = bf_rne(v.x); o.y = bf_rne(v.y); o.z = bf_rne(v.z); o.w = bf_rne(v.w);
    out[i] = o;
}

#define NTK 64          // K tiles = 2048/32

// ---------------- GEMM core v5 (qkv): 256x128, BK=32, dbuf 48KB, 4Mx1N wave map ------
// Same staging/boundary as the round-3-verified dbuf core (48KB -> 3 blocks/CU; fused
// "s_waitcnt vmcnt(0); s_barrier" boundary; WAR/RAW ledger unchanged).
// NEW wave map: wave wid owns rows [wid*64,+64) x ALL 128 cols -> acc[4][8]; each
// thread holds both halves of every RoPE pair (d and d+64) -> rope fuses in epilogue.
// Read-side derivation (staging layout: ds-row rho holds global rows i_s*64+2*w| and
// chunk slot sigma holds chunk g = sigma^(rho&7), content k-chunk g&3, row parity g>>2):
//   A frag row wid*64+i*16+l16, k-chunk quad  -> ds-row wid*32+i*8+(l16>>1),
//   B frag col j*16+l16,        k-chunk quad  -> ds-row j*8+(l16>>1),
//   slot byte offset cx16 = ((((l16&1)<<2)+quad) ^ ((l16>>1)&7)) << 4   (both).
__device__ __forceinline__ void gemm_core_qkv(
    const short* __restrict__ A, const short* __restrict__ W,
    int m0, int n0, char* lds, f32x4 (&acc)[4][8], int tid)
{
    const int wid  = tid >> 6, lane = tid & 63;
    const int quad = lane >> 4, l16 = lane & 15;
    const int lr   = lane >> 3, sl  = lane & 7;
    const int g    = sl ^ lr;                      // swizzled global chunk
    const int grow = 2*(wid*8 + lr) + (g >> 2);    // global row within a 64-row slab
    const int kcol = (g & 3) * 8;                  // k-chunk (shorts) within 32-wide tile
    const int cx16 = ((((l16 & 1) << 2) + quad) ^ ((l16 >> 1) & 7)) << 4;
    const int arow = (l16 >> 1) << 7;              // ds-row byte offset within frag group

    const short* Ap = A + (size_t)(m0 + grow) * Ee + kcol;
    const short* Wp = W + (size_t)(n0 + grow) * Ee + kcol;

    // prologue: stage tile 0 into buf0
    #pragma unroll
    for (int i = 0; i < 4; ++i)
        load_lds16(Ap + (size_t)i*64*Ee, lds + i*4096 + wid*1024);
    #pragma unroll
    for (int i = 0; i < 2; ++i)
        load_lds16(Wp + (size_t)i*64*Ee, lds + 16384 + i*4096 + wid*1024);
    Ap += 32; Wp += 32;
    asm volatile("s_waitcnt vmcnt(0)\n\ts_barrier" ::: "memory");

    for (int t = 0; t < NTK; ++t) {
        const int bo = (t & 1) ? 24576 : 0;
        if (t + 1 < NTK) {
            const int so = bo ^ 24576;
            #pragma unroll
            for (int i = 0; i < 4; ++i)
                load_lds16(Ap + (size_t)i*64*Ee, lds + so + i*4096 + wid*1024);
            #pragma unroll
            for (int i = 0; i < 2; ++i)
                load_lds16(Wp + (size_t)i*64*Ee, lds + so + 16384 + i*4096 + wid*1024);
            Ap += 32; Wp += 32;
        }
        const char* Ab2 = lds + bo + wid*4096 + arow + cx16;
        const char* Bb2 = lds + bo + 16384 + arow + cx16;
        short8 af[4];
        #pragma unroll
        for (int i = 0; i < 4; ++i) af[i] = *(const short8*)(Ab2 + i*1024);
        __builtin_amdgcn_s_setprio(1);
        #pragma unroll
        for (int j = 0; j < 8; ++j) {
            short8 bfr = *(const short8*)(Bb2 + j*1024);   // streamed, not held
            #pragma unroll
            for (int i = 0; i < 4; ++i)
                acc[i][j] = __builtin_amdgcn_mfma_f32_16x16x32_bf16(af[i], bfr, acc[i][j], 0, 0, 0);
        }
        __builtin_amdgcn_s_setprio(0);
        asm volatile("s_waitcnt vmcnt(0)\n\ts_barrier" ::: "memory");
    }
}

// ---------------- GEMM core v2.1 (oproj, rounds-2/3 verified): 3-buf counted vmcnt ----
#define BUFB 24576      // bytes per LDS buffer

__device__ __forceinline__ void gemm_core(
    const short* __restrict__ A, const short* __restrict__ W,
    int m0, int n0, char* lds, f32x4 (&acc)[8][4], int tid)
{
    const int wid  = tid >> 6, lane = tid & 63;
    const int wr   = wid >> 1, wc   = wid & 1;
    const int quad = lane >> 4, l16 = lane & 15;
    const int lr   = lane >> 3, sl  = lane & 7;
    const int g    = sl ^ lr;
    const int grow = 2*(wid*8 + lr) + (g >> 2);
    const int kcol = (g & 3) * 8;
    const int cx16 = ((((l16 & 1) << 2) + quad) ^ ((l16 >> 1) & 7)) << 4;
    const int arow = (l16 >> 1) << 7;

    const short* Ab = A + (size_t)(m0 + grow) * Ee + kcol;
    const short* Wb = W + (size_t)(n0 + grow) * Ee + kcol;

    auto stageTile = [&](int kt, int so) {
        const short* a = Ab + kt * 32;
        const short* w = Wb + kt * 32;
        #pragma unroll
        for (int i = 0; i < 4; ++i)
            load_lds16(a + (size_t)i*64*Ee, lds + so + i*4096 + wid*1024);
        #pragma unroll
        for (int i = 0; i < 2; ++i)
            load_lds16(w + (size_t)i*64*Ee, lds + so + 16384 + i*4096 + wid*1024);
    };

    stageTile(0, 0);
    stageTile(1, BUFB);
    asm volatile("s_waitcnt vmcnt(6)\n\ts_barrier" ::: "memory");

    int bo = 0, so = 2*BUFB;
    for (int t = 0; t < NTK; ++t) {
        if (t + 2 < NTK) stageTile(t + 2, so);

        const char* Abase = lds + bo + wr*8192 + arow + cx16;
        const char* Bbase = lds + bo + 16384 + wc*4096 + arow + cx16;
        short8 af[8], bfr[4];
        #pragma unroll
        for (int i = 0; i < 8; ++i) af[i] = *(const short8*)(Abase + i*1024);
        #pragma unroll
        for (int j = 0; j < 4; ++j) bfr[j] = *(const short8*)(Bbase + j*1024);

        __builtin_amdgcn_s_setprio(1);
        #pragma unroll
        for (int i = 0; i < 8; ++i)
            #pragma unroll
            for (int j = 0; j < 4; ++j)
                acc[i][j] = __builtin_amdgcn_mfma_f32_16x16x32_bf16(af[i], bfr[j], acc[i][j], 0, 0, 0);
        __builtin_amdgcn_s_setprio(0);

        if (t == NTK - 1) break;
        if (t < NTK - 2) asm volatile("s_waitcnt vmcnt(6)\n\ts_barrier" ::: "memory");
        else             asm volatile("s_waitcnt vmcnt(0)\n\ts_barrier" ::: "memory");
        bo = (bo == 2*BUFB) ? 0 : bo + BUFB;
        so = (so == 2*BUFB) ? 0 : so + BUFB;
    }
}

// ---------------- fused QKV projection + RoPE ----------------
// grid (16, 48): by>>4 = sub (0=Q,1=K,2=V), by&15 = head. RoPE (rotate-half, scale
// 1/sqrt(D) folded into Q) applied in-register in the epilogue for Q,K.
// V -> [B,H,D,S] bf16 via per-wave two-half LDS transpose (new 64x128 wave map).
__global__ __launch_bounds__(256, 3) void qkv_gemm(
    const short* __restrict__ xq, const short* __restrict__ xkv,
    const short* __restrict__ wq, const short* __restrict__ wk, const short* __restrict__ wv,
    const float* __restrict__ bq, const float* __restrict__ bk, const float* __restrict__ bv,
    const float* __restrict__ cosT, const float* __restrict__ sinT,
    short* __restrict__ Qr, short* __restrict__ Kr, short* __restrict__ VT)
{
    __shared__ __align__(16) char lds[49152];   // 2 x 24KB dbuf -> 3 blocks/CU
    const int tid  = threadIdx.x;
    const int wid  = tid >> 6, lane = tid & 63;
    const int quad = lane >> 4, l16 = lane & 15;
    const int m0   = blockIdx.x * 256;
    const int sub  = blockIdx.y >> 4;
    const int nb   = blockIdx.y & 15;
    const int n0   = nb * 128;

    const short* A = (sub == 0) ? xq : xkv;
    const short* W = (sub == 0) ? wq : (sub == 1) ? wk : wv;
    const float* bias = (sub == 0) ? bq : (sub == 1) ? bk : bv;

    f32x4 acc[4][8] = {};
    gemm_core_qkv(A, W, m0, n0, lds, acc, tid);

    const int b0 = m0 >> 11;
    const int s0 = m0 & (Ss - 1);

    if (sub < 2) {
        short* out = sub ? Kr : Qr;
        const float scale = sub ? 1.0f : 0.08838834764831845f;
        #pragma unroll
        for (int i = 0; i < 4; ++i)
            #pragma unroll
            for (int r = 0; r < 4; ++r) {
                int gm = m0 + wid*64 + i*16 + quad*4 + r;
                int b = gm >> 11, s = gm & (Ss - 1);
                size_t rowbase = (((size_t)(b*Hh + nb)) * Ss + s) * Dd;
                #pragma unroll
                for (int j = 0; j < 4; ++j) {
                    int d = j*16 + l16;                      // d in [0,64)
                    float c  = cosT[s*Dd + d];               // table duplicated over halves
                    float sn = sinT[s*Dd + d];
                    float x1 = acc[i][j][r]     + bias[n0 + d];
                    float x2 = acc[i][j + 4][r] + bias[n0 + d + 64];
                    out[rowbase + d]      = (short)bf_rne((x1 * c - x2 * sn) * scale);
                    out[rowbase + d + 64] = (short)bf_rne((x2 * c + x1 * sn) * scale);
                }
            }
    } else {
        // V: per-wave transpose, two 64-d halves. Wave owns s in [wid*64,+64), all d.
        __syncthreads();   // all waves done reading staging LDS before reuse
        short* T = (short*)lds + wid * 4608;   // 64 d-rows x stride 72 shorts (9216 B/wave)
        #pragma unroll
        for (int h2 = 0; h2 < 2; ++h2) {
            #pragma unroll
            for (int i = 0; i < 4; ++i)
                #pragma unroll
                for (int j = 0; j < 4; ++j)
                    #pragma unroll
                    for (int r = 0; r < 4; ++r) {
                        int dl  = j*16 + l16;                 // d within half
                        int slc = i*16 + quad*4 + r;          // s within wave's 64 rows
                        T[dl*72 + slc] = (short)bf_rne(acc[i][h2*4 + j][r] + bias[n0 + h2*64 + dl]);
                    }
            #pragma unroll
            for (int ss = 0; ss < 8; ++ss) {
                short8 v = *(const short8*)&T[lane*72 + ss*8];
                int dg = h2*64 + lane;
                int sg = s0 + wid*64 + ss*8;
                *(short8*)&VT[(((size_t)(b0*Hh + nb)) * Dd + dg) * Ss + sg] = v;
            }
        }
    }
}

// ---------------- O-projection: fp32 out = Ob @ wo^T + bo (rounds-2/3 verified) -------
__global__ __launch_bounds__(256, 2) void oproj_gemm(
    const short* __restrict__ A, const short* __restrict__ W,
    const float* __restrict__ bias, float* __restrict__ Cf)
{
    __shared__ __align__(16) char lds[73728];
    const int tid  = threadIdx.x;
    const int wid  = tid >> 6, lane = tid & 63;
    const int quad = lane >> 4, l16 = lane & 15;
    const int wr   = wid >> 1, wc   = wid & 1;
    const int m0 = blockIdx.x * 256;
    const int n0 = blockIdx.y * 128;

    f32x4 acc[8][4] = {};
    gemm_core(A, W, m0, n0, lds, acc, tid);

    #pragma unroll
    for (int i = 0; i < 8; ++i)
        #pragma unroll
        for (int j = 0; j < 4; ++j)
            #pragma unroll
            for (int r = 0; r < 4; ++r) {
                int gm = m0 + wr*128 + i*16 + quad*4 + r;
                int gn = n0 + wc*64 + j*16 + l16;
                Cf[(size_t)gm * Ee + gn] = acc[i][j][r] + bias[gn];
            }
}

// ---------------- Flash attention (causal), bf16 MFMA (round-6 verified) ----------------
__global__ __launch_bounds__(256, 2) void attn_kernel(
    const short* __restrict__ Q, const short* __restrict__ Kk,
    const short* __restrict__ VT, short* __restrict__ O)
{
    __shared__ short Ks[64*128];
    __shared__ short Vt[2][128*64];
    __shared__ short Pw[4][32*72];

    const int tid  = threadIdx.x;
    const int wave = tid >> 6;
    const int lane = tid & 63;
    const int quad = lane >> 4;
    const int l16  = lane & 15;
    const int mmap = (blockIdx.x + blockIdx.y) & 15;
    const int qt   = (blockIdx.y & 16) ? (15 - mmap) : mmap;
    const int bh = blockIdx.y;
    const int b  = bh >> 4, h = bh & 15;
    const size_t head_off = (size_t)bh * Ss * Dd;
    const short* Kg  = Kk + head_off;
    const short* VTg = VT + head_off;

    auto stageK = [&](int kt) {
        #pragma unroll
        for (int j = 0; j < 4; ++j) {
            int r = wave*16 + j*4 + (lane >> 4);
            int c = (lane & 15) ^ (r & 15);
            load_lds16(Kg + (size_t)(kt*64 + r)*Dd + c*8, &Ks[(wave*16 + j*4)*128]);
        }
    };
    auto stageV = [&](int kt, int buf) {
        #pragma unroll
        for (int j = 0; j < 4; ++j) {
            int r = wave*32 + j*8 + (lane >> 3);
            int c = (lane & 7) ^ (r & 7);
            load_lds16(VTg + (size_t)r*Ss + kt*64 + c*8, &Vt[buf][(wave*32 + j*8)*64]);
        }
    };

    const int qbase = qt*128 + wave*32;
    short8 qf[2][4];
    #pragma unroll
    for (int mi = 0; mi < 2; ++mi)
        #pragma unroll
        for (int ds = 0; ds < 4; ++ds)
            qf[mi][ds] = *(const short8*)&Q[head_off + (size_t)(qbase + mi*16 + l16)*Dd + ds*32 + quad*8];

    f32x4 o[2][8] = {};
    float m_i[2][4], l_i[2][4];
    #pragma unroll
    for (int mi = 0; mi < 2; ++mi)
        #pragma unroll
        for (int r = 0; r < 4; ++r) { m_i[mi][r] = -__builtin_inff(); l_i[mi][r] = 0.f; }

    const int ktiles = 2*qt + 2;
    stageK(0);
    stageV(0, 0);

    for (int kt = 0; kt < ktiles; ++kt) {
        asm volatile("s_waitcnt vmcnt(0)\n\ts_barrier" ::: "memory");
        if (kt + 1 < ktiles) stageV(kt+1, (kt+1)&1);

        f32x4 sc[2][4] = {};
        #pragma unroll
        for (int jk = 0; jk < 4; ++jk)
            #pragma unroll
            for (int ds = 0; ds < 4; ++ds) {
                short8 kf = *(const short8*)&Ks[(jk*16 + l16)*128 + (((ds*4 + quad) ^ l16) * 8)];
                #pragma unroll
                for (int mi = 0; mi < 2; ++mi)
                    sc[mi][jk] = __builtin_amdgcn_mfma_f32_16x16x32_bf16(qf[mi][ds], kf, sc[mi][jk], 0, 0, 0);
            }

        asm volatile("s_waitcnt lgkmcnt(0)\n\ts_barrier" ::: "memory");
        if (kt + 1 < ktiles) stageK(kt+1);

        const int k0 = kt*64;
        #pragma unroll
        for (int mi = 0; mi < 2; ++mi) {
            if (k0 + 63 > qbase + mi*16) {
                #pragma unroll
                for (int jk = 0; jk < 4; ++jk) {
                    int kg = k0 + jk*16 + l16;
                    #pragma unroll
                    for (int r = 0; r < 4; ++r)
                        if (kg > qbase + mi*16 + quad*4 + r) sc[mi][jk][r] = -__builtin_inff();
                }
            }
        }

        float alpha[2][4];
        #pragma unroll
        for (int mi = 0; mi < 2; ++mi)
            #pragma unroll
            for (int r = 0; r < 4; ++r) {
                float mx = fmaxf(fmaxf(sc[mi][0][r], sc[mi][1][r]), fmaxf(sc[mi][2][r], sc[mi][3][r]));
                #pragma unroll
                for (int off = 1; off < 16; off <<= 1)
                    mx = fmaxf(mx, __shfl_xor(mx, off));
                float mn = fmaxf(m_i[mi][r], mx);
                alpha[mi][r] = __expf(m_i[mi][r] - mn);
                m_i[mi][r] = mn;
                float s = 0.f;
                #pragma unroll
                for (int jk = 0; jk < 4; ++jk) {
                    float p = __expf(sc[mi][jk][r] - mn);
                    sc[mi][jk][r] = p;
                    s += p;
                }
                l_i[mi][r] = l_i[mi][r] * alpha[mi][r] + s;
            }

        #pragma unroll
        for (int mi = 0; mi < 2; ++mi)
            #pragma unroll
            for (int jk = 0; jk < 4; ++jk)
                #pragma unroll
                for (int r = 0; r < 4; ++r)
                    Pw[wave][(mi*16 + quad*4 + r)*72 + jk*16 + l16] = (short)bf_rne(sc[mi][jk][r]);

        #pragma unroll
        for (int mi = 0; mi < 2; ++mi)
            #pragma unroll
            for (int dt = 0; dt < 8; ++dt)
                #pragma unroll
                for (int r = 0; r < 4; ++r)
                    o[mi][dt][r] *= alpha[mi][r];

        short8 pa[2][2];
        #pragma unroll
        for (int mi = 0; mi < 2; ++mi)
            #pragma unroll
            for (int kk = 0; kk < 2; ++kk)
                pa[mi][kk] = *(const short8*)&Pw[wave][(mi*16 + l16)*72 + kk*32 + quad*8];

        const short* vb = Vt[kt & 1];
        #pragma unroll
        for (int dt = 0; dt < 8; ++dt)
            #pragma unroll
            for (int kk = 0; kk < 2; ++kk) {
                short8 vf = *(const short8*)&vb[(dt*16 + l16)*64 + (((kk*4 + quad) ^ (l16 & 7)) * 8)];
                #pragma unroll
                for (int mi = 0; mi < 2; ++mi)
                    o[mi][dt] = __builtin_amdgcn_mfma_f32_16x16x32_bf16(pa[mi][kk], vf, o[mi][dt], 0, 0, 0);
            }
    }

    #pragma unroll
    for (int mi = 0; mi < 2; ++mi)
        #pragma unroll
        for (int r = 0; r < 4; ++r) {
            float l = l_i[mi][r];
            #pragma unroll
            for (int off = 1; off < 16; off <<= 1)
                l += __shfl_xor(l, off);
            float inv = 1.0f / l;
            int srow = qbase + mi*16 + quad*4 + r;
            size_t obase = ((size_t)b * Ss + srow) * Ee + h * Dd;
            #pragma unroll
            for (int dt = 0; dt < 8; ++dt)
                O[obase + dt*16 + l16] = (short)bf_rne(o[mi][dt][r] * inv);
        }
}

extern "C" void kernel_launch(void* const* d_in, const int* in_sizes, int n_in,
                              void* d_out, int out_size, void* d_ws, size_t ws_size,
                              hipStream_t stream) {
    const float* x_q  = (const float*)d_in[0];
    const float* x_kv = (const float*)d_in[1];
    const float* cosT = (const float*)d_in[2];
    const float* sinT = (const float*)d_in[3];
    const float* wq = (const float*)d_in[4];
    const float* bq = (const float*)d_in[5];
    const float* wk = (const float*)d_in[6];
    const float* bk = (const float*)d_in[7];
    const float* wv = (const float*)d_in[8];
    const float* bv = (const float*)d_in[9];
    const float* wo = (const float*)d_in[10];
    const float* bo = (const float*)d_in[11];

    size_t off = 0;
    auto alloc = [&](size_t bytes) {
        void* p = (char*)d_ws + off;
        off += (bytes + 255) & ~(size_t)255;
        return p;
    };
    const size_t nX = (size_t)Mrows * Ee;
    const size_t nW = (size_t)Ee * Ee;
    // NOTE: the 6 cast outputs must stay contiguous (cast_all writes them as one run)
    short* xq16  = (short*)alloc(nX * 2);
    short* xkv16 = (short*)alloc(nX * 2);
    short* wq16  = (short*)alloc(nW * 2);
    short* wk16  = (short*)alloc(nW * 2);
    short* wv16  = (short*)alloc(nW * 2);
    short* wo16  = (short*)alloc(nW * 2);
    short* Qr    = (short*)alloc(nX * 2);      // [B,H,S,D] (roped, Q pre-scaled)
    short* Kr    = (short*)alloc(nX * 2);      // [B,H,S,D] (roped)
    short* VTb   = (short*)alloc(nX * 2);      // [B,H,D,S]
    short* Ob    = (short*)alloc(nX * 2);      // [B,S,E]

    // 1) single fused cast
    cast_all_kernel<<<32768, 256, 0, stream>>>(
        (const float4*)x_q, (const float4*)x_kv, (const float4*)wq,
        (const float4*)wk, (const float4*)wv, (const float4*)wo, (ushort4*)xq16);

    // 2) fused QKV projection + RoPE (Q,K -> [B,H,S,D] roped; V -> [B,H,D,S])
    qkv_gemm<<<dim3(Mrows/256, 48), 256, 0, stream>>>(
        xq16, xkv16, wq16, wk16, wv16, bq, bk, bv, cosT, sinT, Qr, Kr, VTb);

    // 3) causal flash attention -> Ob [B,S,E] bf16
    attn_kernel<<<dim3(16, Bb*Hh), 256, 0, stream>>>(Qr, Kr, VTb, Ob);

    // 4) output projection -> fp32 d_out
    oproj_gemm<<<dim3(Mrows/256, Ee/128), 256, 0, stream>>>(Ob, wo16, bo, (float*)d_out);
}